// Round 8
// baseline (147.388 us; speedup 1.0000x reference)
//
#include <hip/hip_runtime.h>
#include <hip/hip_bf16.h>
#include <stdint.h>

#define SEQ   2048
#define NHEAD 32
#define HDIM  128
#define RS    (NHEAD * HDIM)   // 4096 floats: row stride in (b,s,h,d) layout
#define KVBLK 64
#define QBLK  128
#define NTILES (SEQ / KVBLK)   // 32 kv tiles
#define TILE_BYTES 16384       // 64*128 bf16 per K tile / 128*64 per V^T tile

typedef float  f32x16 __attribute__((ext_vector_type(16)));
typedef __bf16 bf16x8 __attribute__((ext_vector_type(8)));
typedef uint32_t u32;

__device__ __forceinline__ unsigned short f2bf(float f) {
  unsigned u = __builtin_bit_cast(unsigned, f);
  u += 0x7fffu + ((u >> 16) & 1u);           // round-to-nearest-even
  return (unsigned short)(u >> 16);
}

__device__ __forceinline__ u32 packbf(float a, float b) {
  __bf16 x = (__bf16)a, y = (__bf16)b;
  unsigned short ux = __builtin_bit_cast(unsigned short, x);
  unsigned short uy = __builtin_bit_cast(unsigned short, y);
  return (u32)ux | ((u32)uy << 16);
}

// ---------------- pre-pass ----------------
// K image:  byte(key,d) = key*256 + ((d*2) ^ ((key&15)<<4))   [16-slot swizzle, 256B rows]
// V^T image: byte(d,kk) = d*128 + ((kk*2) ^ ((d&7)<<4))       [8-slot swizzle, 128B rows]
__global__ __launch_bounds__(256) void prepass_kernel(
    const float* __restrict__ K, const float* __restrict__ V,
    char* __restrict__ wsK, char* __restrict__ wsV) {
  const int tid = threadIdx.x;
  const int t   = blockIdx.x & (NTILES - 1);
  const int h   = blockIdx.x >> 5;
  const int kv0 = t * KVBLK;
  char* kd = wsK + (size_t)(h * NTILES + t) * TILE_BYTES;
  char* vd = wsV + (size_t)(h * NTILES + t) * TILE_BYTES;

  {
    const int c  = tid & 15;
    const int kr = tid >> 4;
#pragma unroll
    for (int ki = 0; ki < 4; ++ki) {
      const int kk = kr + ki * 16;
      const float* kp = K + (size_t)(kv0 + kk) * RS + h * HDIM + c * 8;
      float4 x0 = *(const float4*)kp;
      float4 x1 = *(const float4*)(kp + 4);
      uint32_t u0 = f2bf(x0.x) | ((uint32_t)f2bf(x0.y) << 16);
      uint32_t u1 = f2bf(x0.z) | ((uint32_t)f2bf(x0.w) << 16);
      uint32_t u2 = f2bf(x1.x) | ((uint32_t)f2bf(x1.y) << 16);
      uint32_t u3 = f2bf(x1.z) | ((uint32_t)f2bf(x1.w) << 16);
      const uint32_t byte = (uint32_t)(kk * 256) + (((uint32_t)(c * 16)) ^ (uint32_t)((kk & 15) << 4));
      *(uint4*)(kd + byte) = make_uint4(u0, u1, u2, u3);
    }
  }
  {
    const int d0  = (tid & 31) * 4;
    const int kk0 = (tid >> 5) * 8;
    float vv[8][4];
#pragma unroll
    for (int r = 0; r < 8; ++r) {
      const float* vp = V + (size_t)(kv0 + kk0 + r) * RS + h * HDIM + d0;
      float4 x = *(const float4*)vp;
      vv[r][0] = x.x; vv[r][1] = x.y; vv[r][2] = x.z; vv[r][3] = x.w;
    }
#pragma unroll
    for (int i = 0; i < 4; ++i) {
      const int d = d0 + i;
      uint32_t p0 = f2bf(vv[0][i]) | ((uint32_t)f2bf(vv[1][i]) << 16);
      uint32_t p1 = f2bf(vv[2][i]) | ((uint32_t)f2bf(vv[3][i]) << 16);
      uint32_t p2 = f2bf(vv[4][i]) | ((uint32_t)f2bf(vv[5][i]) << 16);
      uint32_t p3 = f2bf(vv[6][i]) | ((uint32_t)f2bf(vv[7][i]) << 16);
      const uint32_t byte = (uint32_t)(d * 128) + (((uint32_t)(kk0 * 2)) ^ (uint32_t)((d & 7) << 4));
      *(uint4*)(vd + byte) = make_uint4(p0, p1, p2, p3);
    }
  }
}

// ---------------- main: swapped QK^T 32x32, in-register softmax, T14 reg-staged single-buffer ----
__global__ __launch_bounds__(256, 2) void fattn_main(
    const float* __restrict__ Q, const char* __restrict__ wsK,
    const char* __restrict__ wsV, float* __restrict__ O) {
  const int tid  = threadIdx.x;
  const int w    = tid >> 6;      // wave 0..3
  const int lane = tid & 63;
  const int n    = lane & 31;     // q-row (QK) / d-col (PV)
  const int hh   = lane >> 5;     // lane half

  // XCD swizzle + complement pairing: (bid, bid+256) land on the same CU and
  // their qb values sum to 15 -> exactly 34 kv-tile-iters per CU.
  const int bid  = blockIdx.x;          // 0..511
  const int b2   = bid & 255;
  const int vid  = (b2 & 7) * 32 + (b2 >> 3);
  const int head = vid >> 3;
  const int jj   = vid & 7;
  const int qb   = (bid < 256) ? (15 - jj) : jj;
  const int q0   = qb * QBLK;
  const int ntile  = 2 * qb + 2;
  const int diag_t = 2 * qb + (w >> 1);   // wave's straddling tile

  __shared__ __align__(16) char smem[32768];   // 16KB K + 16KB V^T (single buffer)
  char* Ksm = smem;
  char* Vsm = smem + 16384;

  const float qscale = 0.088388347648318447f * 1.4426950408889634f; // 1/sqrt(D)*log2(e)
  const int qrow = q0 + w * 32 + n;

  // Q B-fragments: bq[ks] holds Q[qrow][ks*16 + hh*8 + j] * qscale
  bf16x8 bq[8];
  {
    const float* qp = Q + (size_t)qrow * RS + head * HDIM + hh * 8;
#pragma unroll
    for (int ks = 0; ks < 8; ++ks) {
      float4 v0 = *(const float4*)(qp + ks * 16);
      float4 v1 = *(const float4*)(qp + ks * 16 + 4);
      bf16x8 a;
      a[0] = (__bf16)(v0.x * qscale); a[1] = (__bf16)(v0.y * qscale);
      a[2] = (__bf16)(v0.z * qscale); a[3] = (__bf16)(v0.w * qscale);
      a[4] = (__bf16)(v1.x * qscale); a[5] = (__bf16)(v1.y * qscale);
      a[6] = (__bf16)(v1.z * qscale); a[7] = (__bf16)(v1.w * qscale);
      bq[ks] = a;
    }
  }

  f32x16 accO[4];
#pragma unroll
  for (int i = 0; i < 4; ++i) accO[i] = (f32x16)(0.f);
  float m_run  = -1e30f;
  float l_part = 0.f;

  const char* kbase = wsK + (size_t)head * NTILES * TILE_BYTES;
  const char* vbase = wsV + (size_t)head * NTILES * TILE_BYTES;
  const bool  doK   = (w < 2);
  const char* sbase = doK ? kbase : vbase;
  const int   half  = (w & 1) * 8192;   // this wave's half of its 16KB tile

  uint4 streg[8];   // T14 staging registers (32 VGPR): 128B/lane = 1/4 of K or V tile
  auto stage_load = [&](int t) {        // issue-early: global -> reg (async)
    const char* src = sbase + (size_t)t * TILE_BYTES + half + lane * 16;
#pragma unroll
    for (int i = 0; i < 8; ++i) streg[i] = *(const uint4*)(src + i * 1024);
  };
  auto stage_write = [&]() {            // write-late: reg -> LDS (compiler waits vmcnt)
    char* dst = (doK ? Ksm : Vsm) + half + lane * 16;
#pragma unroll
    for (int i = 0; i < 8; ++i) *(uint4*)(dst + i * 1024) = streg[i];
  };

  stage_load(0);
  stage_write();
  __syncthreads();    // tile 0 visible

  for (int t = 0; t < ntile; ++t) {
    if (t + 1 < ntile) stage_load(t + 1);   // HBM/L2 latency hides under compute below

    if (t <= diag_t) {
      // ---- S^T = K Q^T : sc[kt][r] = S[key][qrow], key = kt*32 + (r&3)+8*(r>>2)+4*hh ----
      f32x16 sc[2];
      __builtin_amdgcn_s_setprio(1);
#pragma unroll
      for (int kt = 0; kt < 2; ++kt) {
        f32x16 acc = (f32x16)(0.f);
        const int key = kt * 32 + n;
        const uint32_t rowb = (uint32_t)(key * 256);
        const uint32_t swz  = (uint32_t)((key & 15) << 4);
#pragma unroll
        for (int ks = 0; ks < 8; ++ks) {
          const uint32_t byte = rowb + (((uint32_t)(ks * 32 + hh * 16)) ^ swz);
          bf16x8 kf = *(const bf16x8*)(Ksm + byte);
          acc = __builtin_amdgcn_mfma_f32_32x32x16_bf16(kf, bq[ks], acc, 0, 0, 0);
        }
        sc[kt] = acc;
      }
      __builtin_amdgcn_s_setprio(0);

      // ---- causal mask (straddling tile only) ----
      if (t == diag_t) {
        const int kv0 = t * KVBLK;
#pragma unroll
        for (int kt = 0; kt < 2; ++kt)
#pragma unroll
          for (int r = 0; r < 16; ++r) {
            const int keyg = kv0 + kt * 32 + (r & 3) + 8 * (r >> 2) + 4 * hh;
            if (keyg > qrow) sc[kt][r] = -1e30f;
          }
      }

      // ---- row max: in-lane tree + cross-half swap ----
      float mx = -1e30f;
#pragma unroll
      for (int kt = 0; kt < 2; ++kt)
#pragma unroll
        for (int r = 0; r < 16; ++r) mx = fmaxf(mx, sc[kt][r]);
      mx = fmaxf(mx, __shfl_xor(mx, 32, 64));

      // ---- defer-max (T13): rare rescale ----
      if (__any(mx - m_run > 11.0f)) {
        const float mn = fmaxf(m_run, mx);
        const float al = exp2f(m_run - mn);
        m_run = mn;
        l_part *= al;
#pragma unroll
        for (int r = 0; r < 16; ++r) {
          const float ar = __shfl(al, (r & 3) + 8 * (r >> 2) + 4 * hh, 64);
#pragma unroll
          for (int nt = 0; nt < 4; ++nt) accO[nt][r] *= ar;
        }
      }

      // ---- P = exp2(S - m_run); own-half row sum ----
      float ls = 0.f;
#pragma unroll
      for (int kt = 0; kt < 2; ++kt)
#pragma unroll
        for (int r = 0; r < 16; ++r) {
          const float p = exp2f(sc[kt][r] - m_run);
          sc[kt][r] = p;
          ls += p;
        }
      l_part += ls;

      // ---- pack + cross-half exchange ----
      u32 ua[2][4], ub[2][4];
#pragma unroll
      for (int kt = 0; kt < 2; ++kt)
#pragma unroll
        for (int i = 0; i < 4; ++i) {
          ua[kt][i] = packbf(sc[kt][4 * i],     sc[kt][4 * i + 1]);
          ub[kt][i] = packbf(sc[kt][4 * i + 2], sc[kt][4 * i + 3]);
        }
      u32 ra[2][2], rb[2][2];
#pragma unroll
      for (int kt = 0; kt < 2; ++kt)
#pragma unroll
        for (int q = 0; q < 2; ++q) {
          ra[kt][q] = __shfl_xor(hh ? ua[kt][2 * q] : ua[kt][2 * q + 1], 32, 64);
          rb[kt][q] = __shfl_xor(hh ? ub[kt][2 * q] : ub[kt][2 * q + 1], 32, 64);
        }

      // ---- O += P V : 4 k-steps x 4 d-tiles ----
      __builtin_amdgcn_s_setprio(1);
#pragma unroll
      for (int s = 0; s < 4; ++s) {
        const int kt = s >> 1, q = s & 1;
        u32 af32[4];
        af32[0] = hh ? ra[kt][q] : ua[kt][2 * q];
        af32[1] = hh ? rb[kt][q] : ub[kt][2 * q];
        af32[2] = hh ? ua[kt][2 * q + 1] : ra[kt][q];
        af32[3] = hh ? ub[kt][2 * q + 1] : rb[kt][q];
        bf16x8 af = __builtin_bit_cast(bf16x8, *(uint4*)af32);
#pragma unroll
        for (int nt = 0; nt < 4; ++nt) {
          const int d = nt * 32 + n;
          const uint32_t byte = (uint32_t)(d * 128) +
              (((uint32_t)(s * 32 + hh * 16)) ^ (uint32_t)((d & 7) << 4));
          bf16x8 vf = *(const bf16x8*)(Vsm + byte);
          accO[nt] = __builtin_amdgcn_mfma_f32_32x32x16_bf16(af, vf, accO[nt], 0, 0, 0);
        }
      }
      __builtin_amdgcn_s_setprio(0);
    }

    if (t + 1 < ntile) {
      // reads of tile t done (this wave's ds ops drained), then block-wide barrier
      asm volatile("s_waitcnt lgkmcnt(0)" ::: "memory");
      __builtin_amdgcn_sched_barrier(0);
      __builtin_amdgcn_s_barrier();          // NO vmcnt drain: prefetch stays in flight
      __builtin_amdgcn_sched_barrier(0);
      stage_write();                          // waits vmcnt for streg, writes LDS
      __syncthreads();                        // tile t+1 visible to all waves
    }
  }

  // ---- epilogue: combine halves, O / l (nontemporal: keep L2 for K/V) ----
  const float lf  = l_part + __shfl_xor(l_part, 32, 64);
  const float inv = 1.0f / lf;
  float* ob = O + (size_t)(q0 + w * 32) * RS + head * HDIM;
#pragma unroll
  for (int r = 0; r < 16; ++r) {
    const int m = (r & 3) + 8 * (r >> 2) + 4 * hh;
    const float im = __shfl(inv, m, 64);
#pragma unroll
    for (int nt = 0; nt < 4; ++nt)
      __builtin_nontemporal_store(accO[nt][r] * im, &ob[(size_t)m * RS + nt * 32 + n]);
  }
}

extern "C" void kernel_launch(void* const* d_in, const int* in_sizes, int n_in,
                              void* d_out, int out_size, void* d_ws, size_t ws_size,
                              hipStream_t stream) {
  const float* q = (const float*)d_in[0];
  const float* k = (const float*)d_in[1];
  const float* v = (const float*)d_in[2];
  float* o = (float*)d_out;
  char* wsK = (char*)d_ws;
  char* wsV = wsK + (size_t)NHEAD * NTILES * TILE_BYTES;
  hipLaunchKernelGGL(prepass_kernel, dim3(NHEAD * NTILES), dim3(256), 0, stream,
                     k, v, wsK, wsV);
  hipLaunchKernelGGL(fattn_main, dim3(512), dim3(256), 0, stream, q, wsK, wsV, o);
}

// Round 9
// 89.104 us; speedup vs baseline: 1.6541x; 1.6541x over previous
//
#include <hip/hip_runtime.h>
#include <hip/hip_bf16.h>
#include <stdint.h>

#define SEQ   2048
#define NHEAD 32
#define HDIM  128
#define RS    (NHEAD * HDIM)   // 4096 floats: row stride in (b,s,h,d) layout
#define KVBLK 64
#define NTILES (SEQ / KVBLK)   // 32 kv tiles
#define TILE_BYTES 16384       // 16 KB fragment-image per tile (K or V)

typedef float  f32x16 __attribute__((ext_vector_type(16)));
typedef __bf16 bf16x8 __attribute__((ext_vector_type(8)));
typedef uint32_t u32;

__device__ __forceinline__ unsigned short f2bf(float f) {
  unsigned u = __builtin_bit_cast(unsigned, f);
  u += 0x7fffu + ((u >> 16) & 1u);           // round-to-nearest-even
  return (unsigned short)(u >> 16);
}

__device__ __forceinline__ u32 packbf(float a, float b) {
  __bf16 x = (__bf16)a, y = (__bf16)b;
  unsigned short ux = __builtin_bit_cast(unsigned short, x);
  unsigned short uy = __builtin_bit_cast(unsigned short, y);
  return (u32)ux | ((u32)uy << 16);
}

// ---------------- pre-pass: build MFMA-fragment images ----------------
// K image chunk (kt,ks) [1KB]: slot lane=hh*32+n (16B) = K[kv0+kt*32+n][d=ks*16+hh*8 .. +7]
// V image chunk (s,nt)  [1KB]: slot lane=hh*32+n (16B) = V^T[d=nt*32+n][keys s*16+hh*8 .. +7]
__global__ __launch_bounds__(256) void prepass_kernel(
    const float* __restrict__ K, const float* __restrict__ V,
    char* __restrict__ wsK, char* __restrict__ wsV) {
  const int tid = threadIdx.x;
  const int t   = blockIdx.x & (NTILES - 1);
  const int h   = blockIdx.x >> 5;
  const int kv0 = t * KVBLK;
  char* kd = wsK + (size_t)(h * NTILES + t) * TILE_BYTES;
  char* vd = wsV + (size_t)(h * NTILES + t) * TILE_BYTES;

  // K image: thread reads row kk, d-chunk c (8 floats), writes one 16B slot
  {
    const int c  = tid & 15;    // d-chunk: d0 = c*8 -> ks = c>>1, hh = c&1
    const int kr = tid >> 4;    // 0..15
#pragma unroll
    for (int ki = 0; ki < 4; ++ki) {
      const int kk = kr + ki * 16;            // tile-local key row
      const float* kp = K + (size_t)(kv0 + kk) * RS + h * HDIM + c * 8;
      float4 x0 = *(const float4*)kp;
      float4 x1 = *(const float4*)(kp + 4);
      uint32_t u0 = f2bf(x0.x) | ((uint32_t)f2bf(x0.y) << 16);
      uint32_t u1 = f2bf(x0.z) | ((uint32_t)f2bf(x0.w) << 16);
      uint32_t u2 = f2bf(x1.x) | ((uint32_t)f2bf(x1.y) << 16);
      uint32_t u3 = f2bf(x1.z) | ((uint32_t)f2bf(x1.w) << 16);
      const int kt = kk >> 5, n = kk & 31, ks = c >> 1, hh = c & 1;
      const uint32_t byte = (uint32_t)((kt * 8 + ks) * 1024 + (hh * 32 + n) * 16);
      *(uint4*)(kd + byte) = make_uint4(u0, u1, u2, u3);
    }
  }
  // V image: thread reads 8 rows (kk0..kk0+7) x 4 d, writes 4 transposed 16B slots
  {
    const int d0  = (tid & 31) * 4;   // 4 d values
    const int kk0 = (tid >> 5) * 8;   // 8 keys (aligned to an hh half-chunk)
    float vv[8][4];
#pragma unroll
    for (int r = 0; r < 8; ++r) {
      const float* vp = V + (size_t)(kv0 + kk0 + r) * RS + h * HDIM + d0;
      float4 x = *(const float4*)vp;
      vv[r][0] = x.x; vv[r][1] = x.y; vv[r][2] = x.z; vv[r][3] = x.w;
    }
    const int s = kk0 >> 4, hh = (kk0 >> 3) & 1;
#pragma unroll
    for (int i = 0; i < 4; ++i) {
      const int d = d0 + i;
      uint32_t p0 = f2bf(vv[0][i]) | ((uint32_t)f2bf(vv[1][i]) << 16);
      uint32_t p1 = f2bf(vv[2][i]) | ((uint32_t)f2bf(vv[3][i]) << 16);
      uint32_t p2 = f2bf(vv[4][i]) | ((uint32_t)f2bf(vv[5][i]) << 16);
      uint32_t p3 = f2bf(vv[6][i]) | ((uint32_t)f2bf(vv[7][i]) << 16);
      const int nt = d >> 5;
      const uint32_t byte = (uint32_t)((s * 4 + nt) * 1024 + (hh * 32 + (d & 31)) * 16);
      *(uint4*)(vd + byte) = make_uint4(p0, p1, p2, p3);
    }
  }
}

// ---------------- main: 1 wave per 32 q-rows, no LDS, no barriers ----------------
__global__ __launch_bounds__(64, 2) void fattn_main(
    const float* __restrict__ Q, const char* __restrict__ wsK,
    const char* __restrict__ wsV, float* __restrict__ O) {
  const int lane = threadIdx.x;   // one wave per block
  const int n    = lane & 31;     // q-row local (QK) / d-col local (PV)
  const int hh   = lane >> 5;     // lane half

  // bid&7 = XCD; within each XCD: 4 heads x 64 q-units, big units (qi high) first
  const int bid  = blockIdx.x;          // 0..2047
  const int k    = bid >> 3;            // 0..255
  const int head = (bid & 7) * 4 + (k & 3);
  const int qi   = 63 - (k >> 2);       // q-unit 0..63, descending work
  const int ntile = (qi >> 1) + 1;
  const int qrow  = qi * 32 + n;        // this lane's q-row

  const float qscale = 0.088388347648318447f * 1.4426950408889634f; // 1/sqrt(D)*log2(e)

  // Q B-fragments: bq[ks] = Q[qrow][ks*16 + hh*8 + j] * qscale
  bf16x8 bq[8];
  {
    const float* qp = Q + (size_t)qrow * RS + head * HDIM + hh * 8;
#pragma unroll
    for (int ks = 0; ks < 8; ++ks) {
      float4 v0 = *(const float4*)(qp + ks * 16);
      float4 v1 = *(const float4*)(qp + ks * 16 + 4);
      bf16x8 a;
      a[0] = (__bf16)(v0.x * qscale); a[1] = (__bf16)(v0.y * qscale);
      a[2] = (__bf16)(v0.z * qscale); a[3] = (__bf16)(v0.w * qscale);
      a[4] = (__bf16)(v1.x * qscale); a[5] = (__bf16)(v1.y * qscale);
      a[6] = (__bf16)(v1.z * qscale); a[7] = (__bf16)(v1.w * qscale);
      bq[ks] = a;
    }
  }

  f32x16 accO[4];
#pragma unroll
  for (int i = 0; i < 4; ++i) accO[i] = (f32x16)(0.f);
  float m_run  = -1e30f;
  float l_part = 0.f;

  const char* kimg = wsK + (size_t)head * NTILES * TILE_BYTES;
  const char* vimg = wsV + (size_t)head * NTILES * TILE_BYTES;

  for (int t = 0; t < ntile; ++t) {
    // ---- K fragments straight from global image (coalesced, L2-resident) ----
    const char* kb = kimg + (size_t)t * TILE_BYTES + lane * 16;
    uint4 kld[16];
#pragma unroll
    for (int i = 0; i < 16; ++i) kld[i] = *(const uint4*)(kb + i * 1024);

    // ---- S^T = K Q^T : sc[kt][r] = S[key = t*64 + kt*32 + crow(r,hh)][qrow] ----
    f32x16 sc[2];
    __builtin_amdgcn_s_setprio(1);
#pragma unroll
    for (int kt = 0; kt < 2; ++kt) {
      f32x16 acc = (f32x16)(0.f);
#pragma unroll
      for (int ks = 0; ks < 8; ++ks) {
        bf16x8 kf = __builtin_bit_cast(bf16x8, kld[kt * 8 + ks]);
        acc = __builtin_amdgcn_mfma_f32_32x32x16_bf16(kf, bq[ks], acc, 0, 0, 0);
      }
      sc[kt] = acc;
    }
    __builtin_amdgcn_s_setprio(0);

    // ---- V fragments issued now; latency hides under softmax ----
    const char* vb = vimg + (size_t)t * TILE_BYTES + lane * 16;
    uint4 vld[16];
#pragma unroll
    for (int i = 0; i < 16; ++i) vld[i] = *(const uint4*)(vb + i * 1024);

    // ---- causal mask (last tile is always this wave's diag tile) ----
    if (t == ntile - 1) {
      const int kv0 = t * KVBLK;
#pragma unroll
      for (int kt = 0; kt < 2; ++kt)
#pragma unroll
        for (int r = 0; r < 16; ++r) {
          const int keyg = kv0 + kt * 32 + (r & 3) + 8 * (r >> 2) + 4 * hh;
          if (keyg > qrow) sc[kt][r] = -1e30f;
        }
    }

    // ---- row max: in-lane + cross-half swap ----
    float mx = -1e30f;
#pragma unroll
    for (int kt = 0; kt < 2; ++kt)
#pragma unroll
      for (int r = 0; r < 16; ++r) mx = fmaxf(mx, sc[kt][r]);
    mx = fmaxf(mx, __shfl_xor(mx, 32, 64));

    // ---- defer-max (T13): rare rescale ----
    if (__any(mx - m_run > 11.0f)) {
      const float mn = fmaxf(m_run, mx);
      const float al = exp2f(m_run - mn);
      m_run = mn;
      l_part *= al;
#pragma unroll
      for (int r = 0; r < 16; ++r) {
        const float ar = __shfl(al, (r & 3) + 8 * (r >> 2) + 4 * hh, 64);
#pragma unroll
        for (int nt = 0; nt < 4; ++nt) accO[nt][r] *= ar;
      }
    }

    // ---- P = exp2(S - m_run); own-half row sum ----
    float ls = 0.f;
#pragma unroll
    for (int kt = 0; kt < 2; ++kt)
#pragma unroll
      for (int r = 0; r < 16; ++r) {
        const float p = exp2f(sc[kt][r] - m_run);
        sc[kt][r] = p;
        ls += p;
      }
    l_part += ls;

    // ---- pack + cross-half exchange (verbatim R6, verified) ----
    u32 ua[2][4], ub[2][4];
#pragma unroll
    for (int kt = 0; kt < 2; ++kt)
#pragma unroll
      for (int i = 0; i < 4; ++i) {
        ua[kt][i] = packbf(sc[kt][4 * i],     sc[kt][4 * i + 1]);
        ub[kt][i] = packbf(sc[kt][4 * i + 2], sc[kt][4 * i + 3]);
      }
    u32 ra[2][2], rb[2][2];
#pragma unroll
    for (int kt = 0; kt < 2; ++kt)
#pragma unroll
      for (int q = 0; q < 2; ++q) {
        ra[kt][q] = __shfl_xor(hh ? ua[kt][2 * q] : ua[kt][2 * q + 1], 32, 64);
        rb[kt][q] = __shfl_xor(hh ? ub[kt][2 * q] : ub[kt][2 * q + 1], 32, 64);
      }

    // ---- O += P V : 4 k-steps x 4 d-tiles ----
    __builtin_amdgcn_s_setprio(1);
#pragma unroll
    for (int s = 0; s < 4; ++s) {
      const int kt = s >> 1, q = s & 1;
      u32 af32[4];
      af32[0] = hh ? ra[kt][q] : ua[kt][2 * q];
      af32[1] = hh ? rb[kt][q] : ub[kt][2 * q];
      af32[2] = hh ? ua[kt][2 * q + 1] : ra[kt][q];
      af32[3] = hh ? ub[kt][2 * q + 1] : rb[kt][q];
      bf16x8 af = __builtin_bit_cast(bf16x8, *(uint4*)af32);
#pragma unroll
      for (int nt = 0; nt < 4; ++nt) {
        bf16x8 vf = __builtin_bit_cast(bf16x8, vld[s * 4 + nt]);
        accO[nt] = __builtin_amdgcn_mfma_f32_32x32x16_bf16(af, vf, accO[nt], 0, 0, 0);
      }
    }
    __builtin_amdgcn_s_setprio(0);
  }

  // ---- epilogue: combine halves, O / l ----
  const float lf  = l_part + __shfl_xor(l_part, 32, 64);
  const float inv = 1.0f / lf;
  float* ob = O + (size_t)(qi * 32) * RS + head * HDIM;
#pragma unroll
  for (int r = 0; r < 16; ++r) {
    const int m = (r & 3) + 8 * (r >> 2) + 4 * hh;
    const float im = __shfl(inv, m, 64);
#pragma unroll
    for (int nt = 0; nt < 4; ++nt)
      ob[(size_t)m * RS + nt * 32 + n] = accO[nt][r] * im;
  }
}

extern "C" void kernel_launch(void* const* d_in, const int* in_sizes, int n_in,
                              void* d_out, int out_size, void* d_ws, size_t ws_size,
                              hipStream_t stream) {
  const float* q = (const float*)d_in[0];
  const float* k = (const float*)d_in[1];
  const float* v = (const float*)d_in[2];
  float* o = (float*)d_out;
  char* wsK = (char*)d_ws;
  char* wsV = wsK + (size_t)NHEAD * NTILES * TILE_BYTES;
  hipLaunchKernelGGL(prepass_kernel, dim3(NHEAD * NTILES), dim3(256), 0, stream,
                     k, v, wsK, wsV);
  hipLaunchKernelGGL(fattn_main, dim3(2048), dim3(64), 0, stream, q, wsK, wsV, o);
}